// Round 14
// baseline (306.979 us; speedup 1.0000x reference)
//
#include <hip/hip_runtime.h>

#define B_    128
#define L_    512
#define H_    256
#define TGB_  128
#define S_    1023
#define BL_   (B_ * L_)     // 65536
#define SIXH  1536
#define FOURH 1024

typedef __bf16 bf16_t;
typedef bf16_t bf16x8 __attribute__((ext_vector_type(8)));
typedef float  f32x4  __attribute__((ext_vector_type(4)));
typedef unsigned short u16x4 __attribute__((ext_vector_type(4)));

template<int P> struct IC { static constexpr int v = P; };

__device__ __forceinline__ unsigned short f2bf(float f) {
    union { float f; unsigned u; } v; v.f = f;
    unsigned u = v.u;
    unsigned r = u + 0x7FFFu + ((u >> 16) & 1u);   // round-to-nearest-even
    return (unsigned short)(r >> 16);
}

__device__ __forceinline__ void gload_lds16(const void* g, void* l) {
    __builtin_amdgcn_global_load_lds(
        (__attribute__((address_space(1))) void*)(void*)(g),
        (__attribute__((address_space(3))) void*)(l), 16, 0, 0);
}

// ---------------------------------------------------------------------------
// K_pre: one kernel, three block roles (all independent work):
//   blocks [0,128):        per-batch scan -> idx_map/shiftb/outslot/posC/Vdev
//   blocks [128,1024):     W1/W2 transpose+bf16 (2x 32x32 tiles per block)
//   blocks [1024,9216):    compacted embed+LN (8 events/block, per-wave
//                          self-computed prefix[b] from lengths)
// Block 0 also resets the two work-steal counters.
// ---------------------------------------------------------------------------
__global__ __launch_bounds__(512) void pre_kernel(
    const int* __restrict__ tok,  const int* __restrict__ ptok,
    const int* __restrict__ atok, const int* __restrict__ actok,
    const int* __restrict__ tgap, const int* __restrict__ gid,
    const int* __restrict__ lengths,
    const float* __restrict__ ttab, const float* __restrict__ titab,
    const float* __restrict__ gtab, const float* __restrict__ gamma,
    const float* __restrict__ beta,
    const float* __restrict__ W1, const float* __restrict__ W2,
    unsigned short* __restrict__ W1T, unsigned short* __restrict__ W2T,
    unsigned short* __restrict__ xln,
    int* __restrict__ idx_map, int* __restrict__ shiftb,
    int* __restrict__ outslot, int* __restrict__ posC,
    int* __restrict__ Vdev, int* __restrict__ ctr)
{
    int blk = blockIdx.x, i = threadIdx.x;

    if (blk >= 1024) {
        // ---- embed + LayerNorm path: 8 events per block, 1 wave each ----
        int eblk = blk - 1024;
        int b = eblk >> 6;
        int w = i >> 6, l = i & 63;
        int ei = (eblk & 63) * 8 + w;            // event index within batch
        int len = lengths[b];
        if (ei >= len) return;
        // per-wave prefix[b] = sum lengths[0..b-1]
        int vpart = (l < b ? lengths[l] : 0) + (l + 64 < b ? lengths[l + 64] : 0);
        #pragma unroll
        for (int off = 32; off > 0; off >>= 1) vpart += __shfl_xor(vpart, off);
        int j = vpart + ei;                      // compacted row
        int rid = b * L_ + ei;
        int i0 = tok[rid], i1 = ptok[rid], i2 = atok[rid], i3 = actok[rid];
        int i4 = tgap[rid]; i4 = i4 < 0 ? 0 : (i4 > TGB_ ? TGB_ : i4);
        int i5 = gid[rid];
        f32x4 v[6];
        v[0] = *(const f32x4*)(ttab  + (size_t)i0 * H_ + l * 4);
        v[1] = *(const f32x4*)(ttab  + (size_t)i1 * H_ + l * 4);
        v[2] = *(const f32x4*)(ttab  + (size_t)i2 * H_ + l * 4);
        v[3] = *(const f32x4*)(ttab  + (size_t)i3 * H_ + l * 4);
        v[4] = *(const f32x4*)(titab + (size_t)i4 * H_ + l * 4);
        v[5] = *(const f32x4*)(gtab  + (size_t)i5 * H_ + l * 4);
        float s = 0.0f, sq = 0.0f;
        #pragma unroll
        for (int k = 0; k < 6; ++k)
            #pragma unroll
            for (int c = 0; c < 4; ++c) { float f = v[k][c]; s += f; sq += f * f; }
        #pragma unroll
        for (int off = 32; off > 0; off >>= 1) {
            s  += __shfl_xor(s,  off);
            sq += __shfl_xor(sq, off);
        }
        float mean = s * (1.0f / 1536.0f);
        float var  = sq * (1.0f / 1536.0f) - mean * mean;
        float rstd = rsqrtf(var + 1e-5f);
        unsigned short* orow = xln + (size_t)j * SIXH;
        #pragma unroll
        for (int k = 0; k < 6; ++k) {
            f32x4 g = *(const f32x4*)(gamma + k * H_ + l * 4);
            f32x4 bb = *(const f32x4*)(beta + k * H_ + l * 4);
            u16x4 o;
            #pragma unroll
            for (int c = 0; c < 4; ++c)
                o[c] = f2bf((v[k][c] - mean) * rstd * g[c] + bb[c]);
            *(u16x4*)(orow + k * H_ + l * 4) = o;
        }
        return;
    }

    if (blk >= B_) {
        // ---- transpose path: tile tidx = (blk-B_)*2 + (i>>8) ----
        __shared__ float tile[2][32][33];
        int half = i >> 8;
        int t = i & 255;
        int tidx = (blk - B_) * 2 + half;
        const float* in; unsigned short* out; int R, C, rb, cb;
        if (tidx < 1536) {
            in = W1; out = W1T; R = SIXH; C = FOURH;
            rb = (tidx % 48) * 32; cb = (tidx / 48) * 32;
        } else {
            int u = tidx - 1536;
            in = W2; out = W2T; R = FOURH; C = H_;
            rb = (u % 32) * 32; cb = (u / 32) * 32;
        }
        int tx = t & 31, ty = t >> 5;   // 32 x 8
        #pragma unroll
        for (int d = 0; d < 32; d += 8)
            tile[half][ty + d][tx] = in[(size_t)(rb + ty + d) * C + cb + tx];
        __syncthreads();
        #pragma unroll
        for (int d = 0; d < 32; d += 8)
            out[(size_t)(cb + ty + d) * R + rb + tx] = f2bf(tile[half][tx][ty + d]);
        return;
    }

    // ---- scan path ----
    int b = blk;
    if (b == 0 && i < 2) ctr[i] = 0;             // reset steal counters
    __shared__ int slen[128];
    __shared__ int sres[2];
    if (i < 128) slen[i] = lengths[i];
    __syncthreads();
    if (i < 64) {
        int vpart = (i < b ? slen[i] : 0) + (i + 64 < b ? slen[i + 64] : 0);
        int vall  = slen[i] + slen[i + 64];
        #pragma unroll
        for (int off = 32; off > 0; off >>= 1) {
            vpart += __shfl_xor(vpart, off);
            vall  += __shfl_xor(vall,  off);
        }
        if (i == 0) { sres[0] = vpart; sres[1] = vall; }
    }
    int len = lengths[b];
    int g  = gid[b * L_ + i];
    int gn = (i < L_ - 1) ? gid[b * L_ + i + 1] : g;
    int bnd = (i < len - 1 && g != gn) ? 1 : 0;
    __shared__ int sc[512];
    sc[i] = bnd;
    __syncthreads();
    for (int off = 1; off < 512; off <<= 1) {
        int v = (i >= off) ? sc[i - off] : 0;
        __syncthreads();
        sc[i] += v;
        __syncthreads();
    }
    int incl  = sc[i];
    int total = sc[511];
    int ex = incl - bnd;
    int M = len + total;
    int shift = S_ - M;          // always >= 0
    int pb = sres[0], V = sres[1];
    for (int s = i; s < S_; s += 512) idx_map[b * S_ + s] = -1;
    __syncthreads();
    if (i < len) {
        int p = shift + i + ex;
        idx_map[b * S_ + p] = i;
        if (bnd) idx_map[b * S_ + p + 1] = -2;
        int j = pb + i;
        outslot[j] = b * S_ + p;
        posC[j]    = p;
    }
    if (i == 0) shiftb[b] = shift;
    if (b == B_ - 1) {
        if (i == 0) *Vdev = V;
        if (i < 256) outslot[V + i] = -1;
    }
}

// ---------------------------------------------------------------------------
// K2: 8-phase 128x128 bf16 MFMA GEMM (r10 inner loop VERBATIM -- measured
// 0 bank conflicts). 256 thr = 4 waves (2m x 2n), 16x16x32, LDS 64 KiB
// dbuf, vmcnt(4) at P3/P7, XOR swizzle both-sides, m204 XCD swizzle.
// Tile assignment: first = blockIdx, then work-steal via atomicAdd(ctr).
// EPI 0: silu -> bf16 C.   EPI 2: fused scatter to out f32 + fill tail.
// ---------------------------------------------------------------------------
template<int K, int NTN, int EPI>
__global__ __launch_bounds__(256, 2) void gemm128_kernel(
    const unsigned short* __restrict__ A,
    const unsigned short* __restrict__ Bt,
    const float* __restrict__ bias,
    unsigned short* __restrict__ C,
    const int* __restrict__ outslot,
    const int* __restrict__ posC,
    const float* __restrict__ ptab,
    float* __restrict__ outF,
    const int* __restrict__ Vdev,
    const int* __restrict__ idx_map,
    const int* __restrict__ shiftb,
    const float* __restrict__ sep,
    int* __restrict__ ctr)
{
    constexpr int N = NTN * 128;
    constexpr int NT = K / 64;        // K-tiles
    constexpr int IT = NT / 2;        // 2 K-tiles per iteration
    extern __shared__ __align__(16) unsigned short lds[];   // 32768 shorts

    const int V = *Vdev;
    const int nact = ((V + 127) >> 7) * NTN;
    const int q = nact >> 3, r = nact & 7;

    const int t = threadIdx.x;
    const int w = t >> 6, l = t & 63;
    const int wm = w >> 1, wn = w & 1;
    const int r16 = l & 15, ql = l >> 4;
    const int sg = (t & 3) ^ ((t >> 3) & 3);
    unsigned short* ldsb = lds + w * 512;              // wave-uniform dest base
    const int fr = (ql ^ ((r16 >> 1) & 3)) * 8;

    // fragment read bases (shorts): buf stride 16384; B at +8192
    const unsigned short* la0 = lds + (wm * 64 + r16) * 32 + fr;
    const unsigned short* la1 = la0 + 16384;
    const unsigned short* lb0 = lds + 8192 + (wn * 64 + r16) * 32 + fr;
    const unsigned short* lb1 = lb0 + 16384;

    __shared__ int snext;
    bool first = true;
    for (int bidv = blockIdx.x; bidv < nact; ) {
        // m204 bijective XCD swizzle
        const int x = bidv & 7, o = bidv >> 3;
        const int wid = (x < r ? x * (q + 1) : r * (q + 1) + (x - r) * q) + o;
        const int mt  = wid / NTN;
        const int m0  = mt * 128;
        const int n0  = (wid - mt * NTN) * 128;

        const unsigned short* As0 = A  + (size_t)(m0 + (t >> 2)) * K + sg * 8;
        const unsigned short* As1 = As0 + (size_t)64 * K;
        const unsigned short* Bs0 = Bt + (size_t)(n0 + (t >> 2)) * K + sg * 8;
        const unsigned short* Bs1 = Bs0 + (size_t)64 * K;

        f32x4 acc[4][4];
        #pragma unroll
        for (int i = 0; i < 4; ++i)
            #pragma unroll
            for (int j = 0; j < 4; ++j) acc[i][j] = (f32x4)0.0f;

        auto ST2 = [&](const unsigned short* s0, const unsigned short* s1,
                       int dofs, int gofs) {
            gload_lds16(s0 + gofs, ldsb + dofs);
            gload_lds16(s1 + gofs, ldsb + dofs + 2048);
        };

        if (!first) __syncthreads();   // LDS WAR guard across tiles
        first = false;

        // prologue: units 0..5 (kt0 full, kt1 kh0)
        ST2(As0, As1, 0,     0);    // u0 buf0 A kh0
        ST2(Bs0, Bs1, 8192,  0);    // u1 buf0 B kh0
        ST2(As0, As1, 4096,  32);   // u2 buf0 A kh1
        ST2(Bs0, Bs1, 12288, 32);   // u3 buf0 B kh1
        ST2(As0, As1, 16384, 64);   // u4 buf1 A kh0
        ST2(Bs0, Bs1, 24576, 64);   // u5 buf1 B kh0
        asm volatile("s_waitcnt vmcnt(4)\ns_barrier" ::: "memory");

        bf16x8 bq[4];

        auto phase = [&](auto pc, bool last) {
            constexpr int P   = decltype(pc)::v;
            constexpr int BUF = P >> 2;
            constexpr int KK  = (P & 3) >> 1;
            constexpr int MH  = P & 1;
            const unsigned short* ab = (BUF ? la1 : la0) + KK * 4096 + MH * 1024;
            bf16x8 aq[2];
            if constexpr (MH == 0) {
                const unsigned short* bb = (BUF ? lb1 : lb0) + KK * 4096;
                bq[0] = *(const bf16x8*)(bb);
                bq[1] = *(const bf16x8*)(bb + 512);
                bq[2] = *(const bf16x8*)(bb + 1024);
                bq[3] = *(const bf16x8*)(bb + 1536);
            }
            aq[0] = *(const bf16x8*)(ab);
            aq[1] = *(const bf16x8*)(ab + 512);
            // staging: unit u = 8it+6+P
            if constexpr (P == 0)      {            ST2(As0, As1, 20480, 96);  }
            else if constexpr (P == 1) {            ST2(Bs0, Bs1, 28672, 96);  }
            else if constexpr (P == 2) { if (!last) ST2(As0, As1, 0,     128); }
            else if constexpr (P == 3) { if (!last) ST2(Bs0, Bs1, 8192,  128); }
            else if constexpr (P == 4) { if (!last) ST2(As0, As1, 4096,  160); }
            else if constexpr (P == 5) { if (!last) ST2(Bs0, Bs1, 12288, 160); }
            else if constexpr (P == 6) { if (!last) ST2(As0, As1, 16384, 192); }
            else                       { if (!last) ST2(Bs0, Bs1, 24576, 192); }
            asm volatile("s_barrier" ::: "memory");
            __builtin_amdgcn_s_setprio(1);
            #pragma unroll
            for (int mm = 0; mm < 2; ++mm)
                #pragma unroll
                for (int nn = 0; nn < 4; ++nn)
                    acc[MH * 2 + mm][nn] = __builtin_amdgcn_mfma_f32_16x16x32_bf16(
                        aq[mm], bq[nn], acc[MH * 2 + mm][nn], 0, 0, 0);
            __builtin_amdgcn_s_setprio(0);
            if constexpr (P == 3) {
                if (last) asm volatile("s_waitcnt vmcnt(0)\ns_barrier" ::: "memory");
                else      asm volatile("s_waitcnt vmcnt(4)\ns_barrier" ::: "memory");
            } else if constexpr (P == 7) {
                if (!last) asm volatile("s_waitcnt vmcnt(4)\ns_barrier" ::: "memory");
            } else {
                asm volatile("s_barrier" ::: "memory");
            }
        };

        for (int it = 0; it < IT; ++it) {
            const bool last = (it == IT - 1);
            phase(IC<0>{}, last);
            phase(IC<1>{}, last);
            phase(IC<2>{}, last);
            phase(IC<3>{}, last);
            phase(IC<4>{}, last);
            phase(IC<5>{}, last);
            phase(IC<6>{}, last);
            phase(IC<7>{}, last);
            As0 += 128; As1 += 128; Bs0 += 128; Bs1 += 128;
        }

        if constexpr (EPI == 0) {
            #pragma unroll
            for (int mi = 0; mi < 4; ++mi) {
                #pragma unroll
                for (int ni = 0; ni < 4; ++ni) {
                    int col = n0 + wn * 64 + ni * 16 + r16;
                    float bv = bias[col];
                    #pragma unroll
                    for (int j = 0; j < 4; ++j) {
                        int row = m0 + wm * 64 + mi * 16 + ql * 4 + j;
                        float v = acc[mi][ni][j] + bv;
                        v = v / (1.0f + __expf(-v));   // silu
                        C[(size_t)row * N + col] = f2bf(v);
                    }
                }
            }
        } else {
            // fused scatter: compact row -> out slot, + bias + pos_table
            #pragma unroll
            for (int mi = 0; mi < 4; ++mi) {
                #pragma unroll
                for (int j = 0; j < 4; ++j) {
                    int row = m0 + wm * 64 + mi * 16 + ql * 4 + j;
                    int slot = outslot[row];
                    if (slot >= 0) {
                        float* orow = outF + (size_t)slot * H_;
                        const float* prow = ptab + (size_t)posC[row] * H_;
                        #pragma unroll
                        for (int ni = 0; ni < 4; ++ni) {
                            int col = n0 + wn * 64 + ni * 16 + r16;
                            orow[col] = acc[mi][ni][j] + bias[col] + prow[col];
                        }
                    }
                }
            }
        }

        // grab next tile (work-stealing)
        if (t == 0) snext = 512 + atomicAdd(ctr, 1);
        __syncthreads();
        bidv = snext;
    }

    // fill tail (EPI==2): zeros / sep slots / mask plane. Disjoint from the
    // gemm scatter writes; depends only on scan outputs. Grid-stride.
    if constexpr (EPI == 2) {
        int hh = (t & 63) * 4;
        for (int u = blockIdx.x; u < 32768; u += 512) {
            int b = u >> 8;
            int s = (u & 255) * 4 + (t >> 6);
            if (s < S_) {
                int shift = shiftb[b];
                float* orow = outF + ((size_t)b * S_ + s) * H_;
                if (s < shift) {
                    *(f32x4*)(orow + hh) = (f32x4)0.0f;
                } else {
                    int idx = idx_map[b * S_ + s];
                    if (idx == -2) {
                        f32x4 pv = *(const f32x4*)(ptab + (size_t)s * H_ + hh);
                        f32x4 sv = *(const f32x4*)(sep + hh);
                        *(f32x4*)(orow + hh) = pv + sv;
                    }
                }
                if ((t & 63) == 0)
                    outF[(size_t)B_ * S_ * H_ + (size_t)b * S_ + s] = (s >= shift) ? 1.0f : 0.0f;
            }
        }
    }
}

// ---------------------------------------------------------------------------
extern "C" void kernel_launch(void* const* d_in, const int* in_sizes, int n_in,
                              void* d_out, int out_size, void* d_ws, size_t ws_size,
                              hipStream_t stream)
{
    const int*   tok   = (const int*)d_in[0];
    const int*   ptok  = (const int*)d_in[1];
    const int*   atok  = (const int*)d_in[2];
    const int*   actok = (const int*)d_in[3];
    const int*   tgap  = (const int*)d_in[4];
    const int*   gid   = (const int*)d_in[5];
    const int*   lens  = (const int*)d_in[6];
    const float* ttab  = (const float*)d_in[7];
    const float* titab = (const float*)d_in[8];
    const float* gtab  = (const float*)d_in[9];
    const float* post  = (const float*)d_in[10];
    const float* sep   = (const float*)d_in[11];
    const float* gamma = (const float*)d_in[12];
    const float* beta  = (const float*)d_in[13];
    const float* W1    = (const float*)d_in[14];
    const float* b1    = (const float*)d_in[15];
    const float* W2    = (const float*)d_in[16];
    const float* b2    = (const float*)d_in[17];

    unsigned short* xln  = (unsigned short*)d_ws;                 // BL*1536 bf16
    unsigned short* hbuf = xln  + (size_t)BL_ * SIXH;             // BL*1024 bf16
    unsigned short* W1T  = hbuf + (size_t)BL_ * FOURH;            // 1024*1536 bf16
    unsigned short* W2T  = W1T  + (size_t)FOURH * SIXH;           // 256*1024 bf16
    int* idx_map = (int*)(W2T + (size_t)H_ * FOURH);              // B*S int
    int* shiftb  = idx_map + B_ * S_;                             // B
    int* Vdev    = shiftb + B_;                                   // 1 (+pad)
    int* outslot = Vdev + 4;                                      // BL+256
    int* posC    = outslot + BL_ + 256;                           // BL
    int* ctr     = posC + BL_;                                    // 2 (+pad)
    float* out   = (float*)d_out;

    constexpr int LDSG = 2 * 16384 * 2;                           // 65536
    (void)hipFuncSetAttribute((const void*)&gemm128_kernel<SIXH, 8, 0>,
                              hipFuncAttributeMaxDynamicSharedMemorySize, LDSG);
    (void)hipFuncSetAttribute((const void*)&gemm128_kernel<FOURH, 2, 2>,
                              hipFuncAttributeMaxDynamicSharedMemorySize, LDSG);

    // pre: scan (128) + transposes (896) + embed+LN (8192), one kernel
    pre_kernel<<<1024 + BL_ / 8, 512, 0, stream>>>(
        tok, ptok, atok, actok, tgap, gid, lens,
        ttab, titab, gtab, gamma, beta,
        W1, W2, W1T, W2T, xln,
        idx_map, shiftb, outslot, posC, Vdev, ctr);

    // MLP over compacted rows (r10 16x16 gemm, work-stealing persistent 512)
    gemm128_kernel<SIXH, 8, 0><<<512, 256, LDSG, stream>>>(
        xln, W1T, b1, hbuf, nullptr, nullptr, nullptr, nullptr, Vdev,
        nullptr, nullptr, nullptr, ctr);
    gemm128_kernel<FOURH, 2, 2><<<512, 256, LDSG, stream>>>(
        hbuf, W2T, b2, nullptr, outslot, posC, post, out, Vdev,
        idx_map, shiftb, sep, ctr + 1);
}

// Round 15
// 273.986 us; speedup vs baseline: 1.1204x; 1.1204x over previous
//
#include <hip/hip_runtime.h>

#define B_    128
#define L_    512
#define H_    256
#define TGB_  128
#define S_    1023
#define BL_   (B_ * L_)     // 65536
#define SIXH  1536
#define FOURH 1024

typedef __bf16 bf16_t;
typedef bf16_t bf16x8 __attribute__((ext_vector_type(8)));
typedef float  f32x4  __attribute__((ext_vector_type(4)));
typedef unsigned short u16x4 __attribute__((ext_vector_type(4)));

template<int P> struct IC { static constexpr int v = P; };

__device__ __forceinline__ unsigned short f2bf(float f) {
    union { float f; unsigned u; } v; v.f = f;
    unsigned u = v.u;
    unsigned r = u + 0x7FFFu + ((u >> 16) & 1u);   // round-to-nearest-even
    return (unsigned short)(r >> 16);
}

__device__ __forceinline__ void gload_lds16(const void* g, void* l) {
    __builtin_amdgcn_global_load_lds(
        (__attribute__((address_space(1))) void*)(void*)(g),
        (__attribute__((address_space(3))) void*)(l), 16, 0, 0);
}

// ---------------------------------------------------------------------------
// K0: transpose + f32->bf16 convert:  in (R x C) f32  ->  out (C x R) bf16
// ---------------------------------------------------------------------------
__global__ __launch_bounds__(256) void transpose_bf16_kernel(
    const float* __restrict__ in, unsigned short* __restrict__ out,
    int R, int C)
{
    __shared__ float tile[32][33];
    int rb = blockIdx.x * 32, cb = blockIdx.y * 32;
    int tx = threadIdx.x & 31, ty = threadIdx.x >> 5;   // 32 x 8
    #pragma unroll
    for (int d = 0; d < 32; d += 8)
        tile[ty + d][tx] = in[(size_t)(rb + ty + d) * C + cb + tx];
    __syncthreads();
    #pragma unroll
    for (int d = 0; d < 32; d += 8)
        out[(size_t)(cb + ty + d) * R + rb + tx] = f2bf(tile[tx][ty + d]);
}

// ---------------------------------------------------------------------------
// K1: compacted gather + LayerNorm. One wave per valid event j.
// ---------------------------------------------------------------------------
__global__ __launch_bounds__(256) void embed_ln_kernel(
    const int* __restrict__ tok,  const int* __restrict__ ptok,
    const int* __restrict__ atok, const int* __restrict__ actok,
    const int* __restrict__ tgap, const int* __restrict__ gid,
    const float* __restrict__ ttab, const float* __restrict__ titab,
    const float* __restrict__ gtab, const float* __restrict__ gamma,
    const float* __restrict__ beta, const int* __restrict__ row_id,
    const int* __restrict__ Vdev, unsigned short* __restrict__ xln)
{
    int j = blockIdx.x * 4 + (threadIdx.x >> 6);
    if (j >= *Vdev) return;
    int l = threadIdx.x & 63;
    int rid = row_id[j];
    int i0 = tok[rid], i1 = ptok[rid], i2 = atok[rid], i3 = actok[rid];
    int i4 = tgap[rid]; i4 = i4 < 0 ? 0 : (i4 > TGB_ ? TGB_ : i4);
    int i5 = gid[rid];
    f32x4 v[6];
    v[0] = *(const f32x4*)(ttab  + (size_t)i0 * H_ + l * 4);
    v[1] = *(const f32x4*)(ttab  + (size_t)i1 * H_ + l * 4);
    v[2] = *(const f32x4*)(ttab  + (size_t)i2 * H_ + l * 4);
    v[3] = *(const f32x4*)(ttab  + (size_t)i3 * H_ + l * 4);
    v[4] = *(const f32x4*)(titab + (size_t)i4 * H_ + l * 4);
    v[5] = *(const f32x4*)(gtab  + (size_t)i5 * H_ + l * 4);
    float s = 0.0f, sq = 0.0f;
    #pragma unroll
    for (int k = 0; k < 6; ++k)
        #pragma unroll
        for (int c = 0; c < 4; ++c) { float f = v[k][c]; s += f; sq += f * f; }
    #pragma unroll
    for (int off = 32; off > 0; off >>= 1) {
        s  += __shfl_xor(s,  off);
        sq += __shfl_xor(sq, off);
    }
    float mean = s * (1.0f / 1536.0f);
    float var  = sq * (1.0f / 1536.0f) - mean * mean;
    float rstd = rsqrtf(var + 1e-5f);
    unsigned short* orow = xln + (size_t)j * SIXH;
    #pragma unroll
    for (int k = 0; k < 6; ++k) {
        f32x4 g = *(const f32x4*)(gamma + k * H_ + l * 4);
        f32x4 b = *(const f32x4*)(beta  + k * H_ + l * 4);
        u16x4 o;
        #pragma unroll
        for (int c = 0; c < 4; ++c)
            o[c] = f2bf((v[k][c] - mean) * rstd * g[c] + b[c]);
        *(u16x4*)(orow + k * H_ + l * 4) = o;
    }
}

// ---------------------------------------------------------------------------
// K2: 8-phase 128x128 bf16 MFMA GEMM (r10 inner loop VERBATIM; measured
// 0 bank conflicts). 256 thr = 4 waves (2m x 2n), 16x16x32, LDS 64 KiB
// dbuf, vmcnt(4) at P3/P7, XOR swizzle both-sides, m204 XCD swizzle.
// Grid 1024 (2x oversubscribed), stride = gridDim.x (multiple of 8 ->
// each block's bidv & 7 invariant -> XCD-L2 locality preserved; hardware
// backfill smooths the tail that persistent-512 lockstep couldn't).
// EPI 0: silu -> bf16 C.   EPI 2: fused scatter to out f32.
// ---------------------------------------------------------------------------
template<int K, int NTN, int EPI>
__global__ __launch_bounds__(256, 2) void gemm128_kernel(
    const unsigned short* __restrict__ A,
    const unsigned short* __restrict__ Bt,
    const float* __restrict__ bias,
    unsigned short* __restrict__ C,
    const int* __restrict__ outslot,
    const int* __restrict__ posC,
    const float* __restrict__ ptab,
    float* __restrict__ outF,
    const int* __restrict__ Vdev)
{
    constexpr int N = NTN * 128;
    constexpr int NT = K / 64;        // K-tiles
    constexpr int IT = NT / 2;        // 2 K-tiles per iteration
    extern __shared__ __align__(16) unsigned short lds[];   // 32768 shorts

    const int V = *Vdev;
    const int nact = ((V + 127) >> 7) * NTN;
    const int q = nact >> 3, r = nact & 7;

    const int t = threadIdx.x;
    const int w = t >> 6, l = t & 63;
    const int wm = w >> 1, wn = w & 1;
    const int r16 = l & 15, ql = l >> 4;
    const int sg = (t & 3) ^ ((t >> 3) & 3);
    unsigned short* ldsb = lds + w * 512;              // wave-uniform dest base
    const int fr = (ql ^ ((r16 >> 1) & 3)) * 8;

    // fragment read bases (shorts): buf stride 16384; B at +8192
    const unsigned short* la0 = lds + (wm * 64 + r16) * 32 + fr;
    const unsigned short* la1 = la0 + 16384;
    const unsigned short* lb0 = lds + 8192 + (wn * 64 + r16) * 32 + fr;
    const unsigned short* lb1 = lb0 + 16384;

    for (int bidv = blockIdx.x; bidv < nact; bidv += (int)gridDim.x) {
        // m204 bijective XCD swizzle
        const int x = bidv & 7, o = bidv >> 3;
        const int wid = (x < r ? x * (q + 1) : r * (q + 1) + (x - r) * q) + o;
        const int mt  = wid / NTN;
        const int m0  = mt * 128;
        const int n0  = (wid - mt * NTN) * 128;

        const unsigned short* As0 = A  + (size_t)(m0 + (t >> 2)) * K + sg * 8;
        const unsigned short* As1 = As0 + (size_t)64 * K;
        const unsigned short* Bs0 = Bt + (size_t)(n0 + (t >> 2)) * K + sg * 8;
        const unsigned short* Bs1 = Bs0 + (size_t)64 * K;

        f32x4 acc[4][4];
        #pragma unroll
        for (int i = 0; i < 4; ++i)
            #pragma unroll
            for (int j = 0; j < 4; ++j) acc[i][j] = (f32x4)0.0f;

        auto ST2 = [&](const unsigned short* s0, const unsigned short* s1,
                       int dofs, int gofs) {
            gload_lds16(s0 + gofs, ldsb + dofs);
            gload_lds16(s1 + gofs, ldsb + dofs + 2048);
        };

        if (bidv != (int)blockIdx.x) __syncthreads();   // LDS WAR guard

        // prologue: units 0..5 (kt0 full, kt1 kh0)
        ST2(As0, As1, 0,     0);    // u0 buf0 A kh0
        ST2(Bs0, Bs1, 8192,  0);    // u1 buf0 B kh0
        ST2(As0, As1, 4096,  32);   // u2 buf0 A kh1
        ST2(Bs0, Bs1, 12288, 32);   // u3 buf0 B kh1
        ST2(As0, As1, 16384, 64);   // u4 buf1 A kh0
        ST2(Bs0, Bs1, 24576, 64);   // u5 buf1 B kh0
        asm volatile("s_waitcnt vmcnt(4)\ns_barrier" ::: "memory");

        bf16x8 bq[4];

        auto phase = [&](auto pc, bool last) {
            constexpr int P   = decltype(pc)::v;
            constexpr int BUF = P >> 2;
            constexpr int KK  = (P & 3) >> 1;
            constexpr int MH  = P & 1;
            const unsigned short* ab = (BUF ? la1 : la0) + KK * 4096 + MH * 1024;
            bf16x8 aq[2];
            if constexpr (MH == 0) {
                const unsigned short* bb = (BUF ? lb1 : lb0) + KK * 4096;
                bq[0] = *(const bf16x8*)(bb);
                bq[1] = *(const bf16x8*)(bb + 512);
                bq[2] = *(const bf16x8*)(bb + 1024);
                bq[3] = *(const bf16x8*)(bb + 1536);
            }
            aq[0] = *(const bf16x8*)(ab);
            aq[1] = *(const bf16x8*)(ab + 512);
            // staging: unit u = 8it+6+P
            if constexpr (P == 0)      {            ST2(As0, As1, 20480, 96);  }
            else if constexpr (P == 1) {            ST2(Bs0, Bs1, 28672, 96);  }
            else if constexpr (P == 2) { if (!last) ST2(As0, As1, 0,     128); }
            else if constexpr (P == 3) { if (!last) ST2(Bs0, Bs1, 8192,  128); }
            else if constexpr (P == 4) { if (!last) ST2(As0, As1, 4096,  160); }
            else if constexpr (P == 5) { if (!last) ST2(Bs0, Bs1, 12288, 160); }
            else if constexpr (P == 6) { if (!last) ST2(As0, As1, 16384, 192); }
            else                       { if (!last) ST2(Bs0, Bs1, 24576, 192); }
            asm volatile("s_barrier" ::: "memory");
            __builtin_amdgcn_s_setprio(1);
            #pragma unroll
            for (int mm = 0; mm < 2; ++mm)
                #pragma unroll
                for (int nn = 0; nn < 4; ++nn)
                    acc[MH * 2 + mm][nn] = __builtin_amdgcn_mfma_f32_16x16x32_bf16(
                        aq[mm], bq[nn], acc[MH * 2 + mm][nn], 0, 0, 0);
            __builtin_amdgcn_s_setprio(0);
            if constexpr (P == 3) {
                if (last) asm volatile("s_waitcnt vmcnt(0)\ns_barrier" ::: "memory");
                else      asm volatile("s_waitcnt vmcnt(4)\ns_barrier" ::: "memory");
            } else if constexpr (P == 7) {
                if (!last) asm volatile("s_waitcnt vmcnt(4)\ns_barrier" ::: "memory");
            } else {
                asm volatile("s_barrier" ::: "memory");
            }
        };

        for (int it = 0; it < IT; ++it) {
            const bool last = (it == IT - 1);
            phase(IC<0>{}, last);
            phase(IC<1>{}, last);
            phase(IC<2>{}, last);
            phase(IC<3>{}, last);
            phase(IC<4>{}, last);
            phase(IC<5>{}, last);
            phase(IC<6>{}, last);
            phase(IC<7>{}, last);
            As0 += 128; As1 += 128; Bs0 += 128; Bs1 += 128;
        }

        if constexpr (EPI == 0) {
            #pragma unroll
            for (int mi = 0; mi < 4; ++mi) {
                #pragma unroll
                for (int ni = 0; ni < 4; ++ni) {
                    int col = n0 + wn * 64 + ni * 16 + r16;
                    float bv = bias[col];
                    #pragma unroll
                    for (int j = 0; j < 4; ++j) {
                        int row = m0 + wm * 64 + mi * 16 + ql * 4 + j;
                        float v = acc[mi][ni][j] + bv;
                        v = v / (1.0f + __expf(-v));   // silu
                        C[(size_t)row * N + col] = f2bf(v);
                    }
                }
            }
        } else {
            // fused scatter: compact row -> out slot, + bias + pos_table
            #pragma unroll
            for (int mi = 0; mi < 4; ++mi) {
                #pragma unroll
                for (int j = 0; j < 4; ++j) {
                    int row = m0 + wm * 64 + mi * 16 + ql * 4 + j;
                    int slot = outslot[row];
                    if (slot >= 0) {
                        float* orow = outF + (size_t)slot * H_;
                        const float* prow = ptab + (size_t)posC[row] * H_;
                        #pragma unroll
                        for (int ni = 0; ni < 4; ++ni) {
                            int col = n0 + wn * 64 + ni * 16 + r16;
                            orow[col] = acc[mi][ni][j] + bias[col] + prow[col];
                        }
                    }
                }
            }
        }
    }
}

// ---------------------------------------------------------------------------
// K3: per-batch boundary + cumsum + inverse map + compact maps.
// Prefix computed in-block; block B-1 writes V and pads outslot[V..V+256)=-1.
// ---------------------------------------------------------------------------
__global__ __launch_bounds__(512) void scan_scatter_kernel(
    const int* __restrict__ gid, const int* __restrict__ lengths,
    int* __restrict__ idx_map, int* __restrict__ shiftb,
    int* __restrict__ row_id, int* __restrict__ outslot,
    int* __restrict__ posC, int* __restrict__ Vdev)
{
    int b = blockIdx.x, i = threadIdx.x;
    __shared__ int slen[128];
    __shared__ int sres[2];
    if (i < 128) slen[i] = lengths[i];
    __syncthreads();
    if (i < 64) {
        int vpart = (i < b ? slen[i] : 0) + (i + 64 < b ? slen[i + 64] : 0);
        int vall  = slen[i] + slen[i + 64];
        #pragma unroll
        for (int off = 32; off > 0; off >>= 1) {
            vpart += __shfl_xor(vpart, off);
            vall  += __shfl_xor(vall,  off);
        }
        if (i == 0) { sres[0] = vpart; sres[1] = vall; }
    }
    int len = lengths[b];
    int g  = gid[b * L_ + i];
    int gn = (i < L_ - 1) ? gid[b * L_ + i + 1] : g;
    int bnd = (i < len - 1 && g != gn) ? 1 : 0;
    __shared__ int sc[512];
    sc[i] = bnd;
    __syncthreads();
    for (int off = 1; off < 512; off <<= 1) {
        int v = (i >= off) ? sc[i - off] : 0;
        __syncthreads();
        sc[i] += v;
        __syncthreads();
    }
    int incl  = sc[i];
    int total = sc[511];
    int ex = incl - bnd;
    int M = len + total;
    int shift = S_ - M;          // always >= 0
    int pb = sres[0], V = sres[1];
    for (int s = i; s < S_; s += 512) idx_map[b * S_ + s] = -1;
    __syncthreads();
    if (i < len) {
        int p = shift + i + ex;
        idx_map[b * S_ + p] = i;
        if (bnd) idx_map[b * S_ + p + 1] = -2;
        int j = pb + i;
        row_id[j]  = b * L_ + i;
        outslot[j] = b * S_ + p;
        posC[j]    = p;
    }
    if (i == 0) shiftb[b] = shift;
    if (b == B_ - 1) {
        if (i == 0) *Vdev = V;
        if (i < 256) outslot[V + i] = -1;
    }
}

// ---------------------------------------------------------------------------
// K4: fill non-event slots: zeros (s<shift), sep slots, and the mask plane.
// ---------------------------------------------------------------------------
__global__ __launch_bounds__(256) void fill_kernel(
    const int* __restrict__ idx_map, const int* __restrict__ shiftb,
    const float* __restrict__ ptab, const float* __restrict__ sep,
    float* __restrict__ out)
{
    int b = blockIdx.y;
    int s = blockIdx.x * 4 + (threadIdx.x >> 6);
    if (s >= S_) return;
    int h = (threadIdx.x & 63) * 4;
    int shift = shiftb[b];
    float* orow = out + ((size_t)b * S_ + s) * H_;
    if (s < shift) {
        *(f32x4*)(orow + h) = (f32x4)0.0f;
    } else {
        int idx = idx_map[b * S_ + s];
        if (idx == -2) {
            f32x4 pv = *(const f32x4*)(ptab + (size_t)s * H_ + h);
            f32x4 sv = *(const f32x4*)(sep + h);
            *(f32x4*)(orow + h) = pv + sv;
        }
    }
    if ((threadIdx.x & 63) == 0)
        out[(size_t)B_ * S_ * H_ + (size_t)b * S_ + s] = (s >= shift) ? 1.0f : 0.0f;
}

// ---------------------------------------------------------------------------
extern "C" void kernel_launch(void* const* d_in, const int* in_sizes, int n_in,
                              void* d_out, int out_size, void* d_ws, size_t ws_size,
                              hipStream_t stream)
{
    const int*   tok   = (const int*)d_in[0];
    const int*   ptok  = (const int*)d_in[1];
    const int*   atok  = (const int*)d_in[2];
    const int*   actok = (const int*)d_in[3];
    const int*   tgap  = (const int*)d_in[4];
    const int*   gid   = (const int*)d_in[5];
    const int*   lens  = (const int*)d_in[6];
    const float* ttab  = (const float*)d_in[7];
    const float* titab = (const float*)d_in[8];
    const float* gtab  = (const float*)d_in[9];
    const float* post  = (const float*)d_in[10];
    const float* sep   = (const float*)d_in[11];
    const float* gamma = (const float*)d_in[12];
    const float* beta  = (const float*)d_in[13];
    const float* W1    = (const float*)d_in[14];
    const float* b1    = (const float*)d_in[15];
    const float* W2    = (const float*)d_in[16];
    const float* b2    = (const float*)d_in[17];

    unsigned short* xln  = (unsigned short*)d_ws;                 // BL*1536 bf16
    unsigned short* hbuf = xln  + (size_t)BL_ * SIXH;             // BL*1024 bf16
    unsigned short* W1T  = hbuf + (size_t)BL_ * FOURH;            // 1024*1536 bf16
    unsigned short* W2T  = W1T  + (size_t)FOURH * SIXH;           // 256*1024 bf16
    int* idx_map = (int*)(W2T + (size_t)H_ * FOURH);              // B*S int
    int* shiftb  = idx_map + B_ * S_;                             // B
    int* Vdev    = shiftb + B_;                                   // 1 (+pad)
    int* row_id  = Vdev + 4;                                      // BL
    int* outslot = row_id + BL_;                                  // BL+256
    int* posC    = outslot + BL_ + 256;                           // BL
    float* out   = (float*)d_out;

    constexpr int LDSG = 2 * 16384 * 2;                           // 65536
    (void)hipFuncSetAttribute((const void*)&gemm128_kernel<SIXH, 8, 0>,
                              hipFuncAttributeMaxDynamicSharedMemorySize, LDSG);
    (void)hipFuncSetAttribute((const void*)&gemm128_kernel<FOURH, 2, 2>,
                              hipFuncAttributeMaxDynamicSharedMemorySize, LDSG);

    // weight transposes (independent)
    transpose_bf16_kernel<<<dim3(SIXH / 32, FOURH / 32), 256, 0, stream>>>(W1, W1T, SIXH, FOURH);
    transpose_bf16_kernel<<<dim3(FOURH / 32, H_ / 32),   256, 0, stream>>>(W2, W2T, FOURH, H_);

    // scan + prefix + compact maps + V + pad
    scan_scatter_kernel<<<B_, 512, 0, stream>>>(gid, lens, idx_map, shiftb,
                                                row_id, outslot, posC, Vdev);

    // compacted embed + layernorm
    embed_ln_kernel<<<BL_ / 4, 256, 0, stream>>>(tok, ptok, atok, actok, tgap, gid,
                                                 ttab, titab, gtab, gamma, beta,
                                                 row_id, Vdev, xln);

    // MLP over compacted rows (r10 gemm, grid 1024, XCD-preserving stride)
    gemm128_kernel<SIXH, 8, 0><<<1024, 256, LDSG, stream>>>(
        xln, W1T, b1, hbuf, nullptr, nullptr, nullptr, nullptr, Vdev);
    gemm128_kernel<FOURH, 2, 2><<<1024, 256, LDSG, stream>>>(
        hbuf, W2T, b2, nullptr, outslot, posC, post, out, Vdev);

    // fill zeros / sep slots / mask plane
    fill_kernel<<<dim3((S_ + 3) / 4, B_), 256, 0, stream>>>(idx_map, shiftb, post, sep, out);
}